// Round 4
// baseline (80109.930 us; speedup 1.0000x reference)
//
#include <hip/hip_runtime.h>

#define NT 512
#define TRAJ 4

constexpr int Lk = 200;
constexpr int NSTEPS = 100;

typedef float f32x4 __attribute__((ext_vector_type(4)));
typedef _Float16 h16x2 __attribute__((ext_vector_type(2)));

__device__ __forceinline__ h16x2 bch2(unsigned int u) {
    return __builtin_bit_cast(h16x2, u);
}

// Stable softplus, matches jax.nn.softplus in fp32: max(x,0) + log1p(exp(-|x|))
__device__ __forceinline__ float sp_act(float x) {
    return fmaxf(x, 0.0f) + log1pf(expf(-fabsf(x)));
}

// fW3 [2048][128] fp32 -> packed fp16 fW3P.
// pair index (((kc*4+k2)*512 + n4)*4 + j) holds fW3[4*n4+j][8*kc+2*k2 .. +1]
// so thread t's chunk-kc slice k2 is ONE coalesced dwordx4 at uint4 index
// ((kc*4+k2)*512 + t): components j=0..3 are rows n=4t+j, cols 8kc+2k2,+1.
__global__ void fw3_pack(const float* __restrict__ w, unsigned int* __restrict__ p) {
    const int i = blockIdx.x * 256 + threadIdx.x;      // 0 .. 131071 (uint32 pairs)
    const int j  = i & 3;
    const int n4 = (i >> 2) & 511;
    const int k2 = (i >> 11) & 3;
    const int kc = i >> 13;
    const int row = 4 * n4 + j;
    const int col = 8 * kc + 2 * k2;
    h16x2 v;
    v.x = (_Float16)w[row * 128 + col];       // RNE
    v.y = (_Float16)w[row * 128 + col + 1];
    p[i] = __builtin_bit_cast(unsigned int, v);
}

// Stage global weight W[O][I] (row-major) into LDS transposed T[I][O].
template<int O, int I>
__device__ __forceinline__ void stage_T(const float* __restrict__ g, float* __restrict__ T) {
    for (int base = threadIdx.x * 4; base < O * I; base += NT * 4) {
        const float4 w = *(const float4*)(g + base);
        const int o = base / I;
        const int i = base % I;
        T[(i + 0) * O + o] = w.x;
        T[(i + 1) * O + o] = w.y;
        T[(i + 2) * O + o] = w.z;
        T[(i + 3) * O + o] = w.w;
    }
}

// out[t][o] = act(bias[o] + sum_i in[t][i] * T[i][o]); ACT: 0=none,1=softplus,2=relu
template<int I, int O, int ACT>
__device__ __forceinline__ void mlp_layer(const float* __restrict__ T,
                                          const float* __restrict__ bias,
                                          const float* __restrict__ in, int inStride,
                                          float* __restrict__ out, int outStride) {
    const int tid = threadIdx.x;
    constexpr int TOT = TRAJ * O;
    for (int e = tid; e < TOT; e += NT) {
        const int t = e / O;
        const int o = e % O;
        const float* inr = in + t * inStride;
        float acc = bias[o];
        #pragma unroll 4
        for (int i = 0; i < I; ++i) acc = fmaf(inr[i], T[i * O + o], acc);
        if (ACT == 1) acc = sp_act(acc);
        else if (ACT == 2) acc = fmaxf(acc, 0.0f);
        out[t * outStride + o] = acc;
    }
}

// One vector-field eval: kout[t][h] = sum_d (fW3 @ sp(fW2 @ sp(fW1 @ y + b1) + b2) + b3)[t, h*32+d] * dX[t][d]
__device__ __forceinline__ void evalvf(float t,
                                       const float* __restrict__ yin,     // LDS [TRAJ][64]
                                       float* __restrict__ kout,          // LDS [TRAJ][64]
                                       const float* __restrict__ wT1,
                                       const float* __restrict__ wT2,
                                       const float* __restrict__ fb1s,
                                       const float* __restrict__ fb2s,
                                       float* __restrict__ h1s,
                                       float* __restrict__ h2s,           // LDS [TRAJ][128] fp32
                                       float* __restrict__ dXs,
                                       const float* __restrict__ ts,
                                       const float* __restrict__ coef_b,
                                       const float* __restrict__ coef_c,
                                       const float* __restrict__ coef_d,
                                       int bbase,
                                       const uint4* __restrict__ wq,      // fW3P as uint4
                                       float4 fb3r)
{
    const int tid = threadIdx.x;

    // cubic-spline derivative dX/dt at scalar time t
    if (tid < TRAJ * 32) {
        int i = (int)floorf(t);
        i = min(max(i, 0), Lk - 2);
        const float frac = t - ts[i];
        const int tt = tid >> 5, d = tid & 31;
        const size_t off = ((size_t)(bbase + tt) * 199 + (size_t)i) * 32 + d;
        dXs[tid] = coef_b[off] + frac * (2.0f * coef_c[off] + 3.0f * frac * coef_d[off]);
    }

    // Prefetch weight chunks 0,1 now — independent of the small layers, so the
    // stream runs under layer1/layer2 compute. Regular cached loads (L2-resident;
    // R2 proved nontemporal loads kill residency: FETCH 25->281 MB).
    uint4 wbuf[2][4];
    #pragma unroll
    for (int k2 = 0; k2 < 4; ++k2) {
        wbuf[0][k2] = wq[(0 * 4 + k2) * 512 + tid];
        wbuf[1][k2] = wq[(1 * 4 + k2) * 512 + tid];
    }

    mlp_layer<64, 128, 1>(wT1, fb1s, yin, 64, h1s, 128);
    __syncthreads();
    mlp_layer<128, 128, 1>(wT2, fb2s, h1s, 128, h2s, 128);
    __syncthreads();

    // Big layer: thread owns n = 4*tid+j. fp16 weights, fp32 h2/accumulate via
    // fmaf(h, (float)w16, acc) — compiler emits v_fma_mix_f32 or cvt+fma.
    f32x4 acc[TRAJ];
    #pragma unroll
    for (int t4 = 0; t4 < TRAJ; ++t4) acc[t4] = (f32x4)0.0f;

    #pragma unroll
    for (int kc = 0; kc < 16; ++kc) {
        uint4 cw[4];
        #pragma unroll
        for (int k2 = 0; k2 < 4; ++k2) cw[k2] = wbuf[kc & 1][k2];
        if (kc + 2 < 16) {
            #pragma unroll
            for (int k2 = 0; k2 < 4; ++k2)
                wbuf[kc & 1][k2] = wq[((kc + 2) * 4 + k2) * 512 + tid];
        }
        float hbuf[TRAJ][8];
        #pragma unroll
        for (int t4 = 0; t4 < TRAJ; ++t4) {
            *(float4*)&hbuf[t4][0] = *(const float4*)(h2s + t4 * 128 + kc * 8);
            *(float4*)&hbuf[t4][4] = *(const float4*)(h2s + t4 * 128 + kc * 8 + 4);
        }
        #pragma unroll
        for (int k2 = 0; k2 < 4; ++k2) {
            const h16x2 pj0 = bch2(cw[k2].x);   // row j=0, cols 2k2, 2k2+1 (of 8)
            const h16x2 pj1 = bch2(cw[k2].y);
            const h16x2 pj2 = bch2(cw[k2].z);
            const h16x2 pj3 = bch2(cw[k2].w);
            #pragma unroll
            for (int t4 = 0; t4 < TRAJ; ++t4) {
                const float he = hbuf[t4][2 * k2];
                const float ho = hbuf[t4][2 * k2 + 1];
                f32x4 a = acc[t4];
                a.x = fmaf(he, (float)pj0.x, a.x); a.x = fmaf(ho, (float)pj0.y, a.x);
                a.y = fmaf(he, (float)pj1.x, a.y); a.y = fmaf(ho, (float)pj1.y, a.y);
                a.z = fmaf(he, (float)pj2.x, a.z); a.z = fmaf(ho, (float)pj2.y, a.z);
                a.w = fmaf(he, (float)pj3.x, a.w); a.w = fmaf(ho, (float)pj3.y, a.w);
                acc[t4] = a;
            }
        }
    }

    // einsum over d: n = 4*tid+j => h = tid>>3, d = 4*(tid&7)+j.
    const int dbase = 4 * (tid & 7);
    float part[TRAJ];
    #pragma unroll
    for (int t4 = 0; t4 < TRAJ; ++t4) {
        const float4 dx = *(const float4*)(dXs + t4 * 32 + dbase);
        part[t4] = (acc[t4].x + fb3r.x) * dx.x + (acc[t4].y + fb3r.y) * dx.y +
                   (acc[t4].z + fb3r.z) * dx.z + (acc[t4].w + fb3r.w) * dx.w;
    }
    #pragma unroll
    for (int m = 1; m < 8; m <<= 1) {
        #pragma unroll
        for (int t4 = 0; t4 < TRAJ; ++t4) part[t4] += __shfl_xor(part[t4], m, 64);
    }
    if ((tid & 7) == 0) {
        const int h = tid >> 3;
        #pragma unroll
        for (int t4 = 0; t4 < TRAJ; ++t4) kout[t4 * 64 + h] = part[t4];
    }
    __syncthreads();
}

__global__ __launch_bounds__(NT, 2)
void cde_kernel(const float* __restrict__ ts,
                const float* __restrict__ coef_d, const float* __restrict__ coef_c,
                const float* __restrict__ coef_b, const float* __restrict__ coef_a,
                const float* __restrict__ iW1, const float* __restrict__ ib1,
                const float* __restrict__ iW2, const float* __restrict__ ib2,
                const float* __restrict__ iW3, const float* __restrict__ ib3,
                const float* __restrict__ fW1, const float* __restrict__ fb1,
                const float* __restrict__ fW2, const float* __restrict__ fb2,
                const float* __restrict__ fb3,
                const float* __restrict__ dW1, const float* __restrict__ db1,
                const float* __restrict__ dW2, const float* __restrict__ db2,
                const float* __restrict__ dW3, const float* __restrict__ db3,
                const uint4* __restrict__ fW3P,
                float* __restrict__ outp)
{
    // weight region is a union across phases: init (112KB) / main (96KB) / decoder (104KB)
    __shared__ float wreg[28672];
    __shared__ float h1s[TRAJ * 128], h2s[TRAJ * 128];
    __shared__ float ys[TRAJ * 64], ys2[TRAJ * 64], k1s[TRAJ * 64], k2s[TRAJ * 64];
    __shared__ float dXs[TRAJ * 32], a0s[TRAJ * 32];
    __shared__ float fb1s[128], fb2s[128];

    const int tid = threadIdx.x;
    const int bbase = blockIdx.x * TRAJ;

    const float ts0 = ts[0];
    const float dt = (ts[Lk - 1] - ts0) / (float)NSTEPS;
    const float4 fb3r = *((const float4*)fb3 + tid);         // n = 4*tid .. 4*tid+3

    // ---- initial condition: y0 = sp(MLP_i(coef_a[:,0,:])) ----
    if (tid < TRAJ * 32) {
        const int t = tid >> 5, d = tid & 31;
        a0s[t * 32 + d] = coef_a[((size_t)(bbase + t) * 199) * 32 + d];
    }
    stage_T<128, 32>(iW1, wreg);                       // iT1 [32][128]
    stage_T<128, 128>(iW2, wreg + 32 * 128);           // iT2 [128][128]
    stage_T<64, 128>(iW3, wreg + 32 * 128 + 128 * 128);// iT3 [128][64]
    if (tid < 128) { fb1s[tid] = fb1[tid]; fb2s[tid] = fb2[tid]; }
    __syncthreads();
    mlp_layer<32, 128, 1>(wreg, ib1, a0s, 32, h1s, 128);
    __syncthreads();
    mlp_layer<128, 128, 1>(wreg + 32 * 128, ib2, h1s, 128, h2s, 128);
    __syncthreads();
    mlp_layer<128, 64, 1>(wreg + 32 * 128 + 128 * 128, ib3, h2s, 128, ys, 64);
    __syncthreads();

    // ---- stage vector-field small weights (resident for all 200 evals) ----
    stage_T<128, 64>(fW1, wreg);                       // wT1 [64][128]
    stage_T<128, 128>(fW2, wreg + 64 * 128);           // wT2 [128][128]
    __syncthreads();

    // ---- Heun over 100 fixed steps ----
    for (int step = 0; step < NSTEPS; ++step) {
        const float t1 = ts0 + (float)step * dt;
        evalvf(t1, ys, k1s, wreg, wreg + 64 * 128, fb1s, fb2s, h1s, h2s, dXs,
               ts, coef_b, coef_c, coef_d, bbase, fW3P, fb3r);
        if (tid < TRAJ * 64) ys2[tid] = ys[tid] + dt * k1s[tid];
        __syncthreads();
        evalvf(t1 + dt, ys2, k2s, wreg, wreg + 64 * 128, fb1s, fb2s, h1s, h2s, dXs,
               ts, coef_b, coef_c, coef_d, bbase, fW3P, fb3r);
        if (tid < TRAJ * 64) ys[tid] += 0.5f * dt * (k1s[tid] + k2s[tid]);
        __syncthreads();
    }

    // ---- decoder: Linear->relu->Linear->relu->Linear ----
    stage_T<128, 64>(dW1, wreg);                          // dT1 [64][128]
    stage_T<128, 128>(dW2, wreg + 64 * 128);              // dT2 [128][128]
    stage_T<16, 128>(dW3, wreg + 64 * 128 + 128 * 128);   // dT3 [128][16]
    __syncthreads();
    mlp_layer<64, 128, 2>(wreg, db1, ys, 64, h1s, 128);
    __syncthreads();
    mlp_layer<128, 128, 2>(wreg + 64 * 128, db2, h1s, 128, h2s, 128);
    __syncthreads();
    mlp_layer<128, 16, 0>(wreg + 64 * 128 + 128 * 128, db3, h2s, 128,
                          outp + (size_t)bbase * 16, 16);
}

extern "C" void kernel_launch(void* const* d_in, const int* in_sizes, int n_in,
                              void* d_out, int out_size, void* d_ws, size_t ws_size,
                              hipStream_t stream) {
    (void)in_sizes; (void)n_in; (void)out_size; (void)ws_size;
    const float* ts     = (const float*)d_in[0];
    const float* coef_d = (const float*)d_in[1];
    const float* coef_c = (const float*)d_in[2];
    const float* coef_b = (const float*)d_in[3];
    const float* coef_a = (const float*)d_in[4];
    const float* iW1 = (const float*)d_in[5];  const float* ib1 = (const float*)d_in[6];
    const float* iW2 = (const float*)d_in[7];  const float* ib2 = (const float*)d_in[8];
    const float* iW3 = (const float*)d_in[9];  const float* ib3 = (const float*)d_in[10];
    const float* fW1 = (const float*)d_in[11]; const float* fb1 = (const float*)d_in[12];
    const float* fW2 = (const float*)d_in[13]; const float* fb2 = (const float*)d_in[14];
    const float* fW3 = (const float*)d_in[15]; const float* fb3 = (const float*)d_in[16];
    const float* dW1 = (const float*)d_in[17]; const float* db1 = (const float*)d_in[18];
    const float* dW2 = (const float*)d_in[19]; const float* db2 = (const float*)d_in[20];
    const float* dW3 = (const float*)d_in[21]; const float* db3 = (const float*)d_in[22];

    unsigned int* fW3P = (unsigned int*)d_ws;   // 512 KB: packed fp16 fW3

    fw3_pack<<<512, 256, 0, stream>>>(fW3, fW3P);
    cde_kernel<<<256, NT, 0, stream>>>(ts, coef_d, coef_c, coef_b, coef_a,
                                       iW1, ib1, iW2, ib2, iW3, ib3,
                                       fW1, fb1, fW2, fb2, fb3,
                                       dW1, db1, dW2, db2, dW3, db3,
                                       (const uint4*)fW3P, (float*)d_out);
}

// Round 5
// 3189.919 us; speedup vs baseline: 25.1135x; 25.1135x over previous
//
#include <hip/hip_runtime.h>

#define NT 512
#define TRAJ 4

constexpr int Lk = 200;
constexpr int NSTEPS = 100;

typedef float f32x4 __attribute__((ext_vector_type(4)));
typedef _Float16 h16x2 __attribute__((ext_vector_type(2)));

__device__ __forceinline__ h16x2 bch2(unsigned int u) {
    return __builtin_bit_cast(h16x2, u);
}

// Stable softplus, matches jax.nn.softplus in fp32: max(x,0) + log1p(exp(-|x|))
__device__ __forceinline__ float sp_act(float x) {
    return fmaxf(x, 0.0f) + log1pf(expf(-fabsf(x)));
}

// fW3 [2048][128] fp32 -> packed fp16 fW3P.
// pair index (((kc*4+k2)*512 + n4)*4 + j) holds fW3[4*n4+j][8*kc+2*k2 .. +1]
// so thread t's chunk-kc slice k2 is ONE coalesced dwordx4 at uint4 index
// ((kc*4+k2)*512 + t): components j=0..3 are rows n=4t+j, cols 8kc+2k2,+1.
// (Numerics validated in R4: absmax 1.18e21 vs 9.44e21 threshold.)
__global__ void fw3_pack(const float* __restrict__ w, unsigned int* __restrict__ p) {
    const int i = blockIdx.x * 256 + threadIdx.x;      // 0 .. 131071 (uint32 pairs)
    const int j  = i & 3;
    const int n4 = (i >> 2) & 511;
    const int k2 = (i >> 11) & 3;
    const int kc = i >> 13;
    const int row = 4 * n4 + j;
    const int col = 8 * kc + 2 * k2;
    h16x2 v;
    v.x = (_Float16)w[row * 128 + col];       // RNE
    v.y = (_Float16)w[row * 128 + col + 1];
    p[i] = __builtin_bit_cast(unsigned int, v);
}

// Stage global weight W[O][I] (row-major) into LDS transposed T[I][O].
template<int O, int I>
__device__ __forceinline__ void stage_T(const float* __restrict__ g, float* __restrict__ T) {
    for (int base = threadIdx.x * 4; base < O * I; base += NT * 4) {
        const float4 w = *(const float4*)(g + base);
        const int o = base / I;
        const int i = base % I;
        T[(i + 0) * O + o] = w.x;
        T[(i + 1) * O + o] = w.y;
        T[(i + 2) * O + o] = w.z;
        T[(i + 3) * O + o] = w.w;
    }
}

// out[t][o] = act(bias[o] + sum_i in[t][i] * T[i][o]); ACT: 0=none,1=softplus,2=relu
template<int I, int O, int ACT>
__device__ __forceinline__ void mlp_layer(const float* __restrict__ T,
                                          const float* __restrict__ bias,
                                          const float* __restrict__ in, int inStride,
                                          float* __restrict__ out, int outStride) {
    const int tid = threadIdx.x;
    constexpr int TOT = TRAJ * O;
    for (int e = tid; e < TOT; e += NT) {
        const int t = e / O;
        const int o = e % O;
        const float* inr = in + t * inStride;
        float acc = bias[o];
        #pragma unroll 4
        for (int i = 0; i < I; ++i) acc = fmaf(inr[i], T[i * O + o], acc);
        if (ACT == 1) acc = sp_act(acc);
        else if (ACT == 2) acc = fmaxf(acc, 0.0f);
        out[t * outStride + o] = acc;
    }
}

// One vector-field eval: kout[t][h] = sum_d (fW3 @ sp(fW2 @ sp(fW1 @ y + b1) + b2) + b3)[t, h*32+d] * dX[t][d]
__device__ __forceinline__ void evalvf(float t,
                                       const float* __restrict__ yin,     // LDS [TRAJ][64]
                                       float* __restrict__ kout,          // LDS [TRAJ][64]
                                       const float* __restrict__ wT1,
                                       const float* __restrict__ wT2,
                                       const float* __restrict__ fb1s,
                                       const float* __restrict__ fb2s,
                                       float* __restrict__ h1s,
                                       float* __restrict__ h2s,           // LDS [TRAJ][128] fp32
                                       float* __restrict__ dXs,
                                       const float* __restrict__ ts,
                                       const float* __restrict__ coef_b,
                                       const float* __restrict__ coef_c,
                                       const float* __restrict__ coef_d,
                                       int bbase,
                                       const uint4* __restrict__ wq,      // fW3P as uint4
                                       float4 fb3r)
{
    const int tid = threadIdx.x;

    // cubic-spline derivative dX/dt at scalar time t
    if (tid < TRAJ * 32) {
        int i = (int)floorf(t);
        i = min(max(i, 0), Lk - 2);
        const float frac = t - ts[i];
        const int tt = tid >> 5, d = tid & 31;
        const size_t off = ((size_t)(bbase + tt) * 199 + (size_t)i) * 32 + d;
        dXs[tid] = coef_b[off] + frac * (2.0f * coef_c[off] + 3.0f * frac * coef_d[off]);
    }

    // Prefetch chunk 0 now — independent of the small layers, streams under
    // their compute. Regular cached loads (R2: nt loads killed L2 residency).
    // NOTE (R4 lesson): nw/cw are ONLY ever indexed by compile-time constants;
    // dynamically-indexed locals (wbuf[kc&1]) were demoted to scratch ->
    // 75 GB HBM thrash. Keep this shape.
    uint4 nw[4];
    #pragma unroll
    for (int j = 0; j < 4; ++j) nw[j] = wq[j * 512 + tid];

    mlp_layer<64, 128, 1>(wT1, fb1s, yin, 64, h1s, 128);
    __syncthreads();
    mlp_layer<128, 128, 1>(wT2, fb2s, h1s, 128, h2s, 128);
    __syncthreads();

    // Big layer: thread owns rows n = 4*tid+j. fp16 weights, fp32 h2/accum.
    f32x4 acc[TRAJ];
    #pragma unroll
    for (int t4 = 0; t4 < TRAJ; ++t4) acc[t4] = (f32x4)0.0f;

    for (int kc = 0; kc < 16; ++kc) {
        uint4 cw[4];
        #pragma unroll
        for (int j = 0; j < 4; ++j) cw[j] = nw[j];
        if (kc + 1 < 16) {
            #pragma unroll
            for (int j = 0; j < 4; ++j)
                nw[j] = wq[((kc + 1) * 4 + j) * 512 + tid];
        }
        #pragma unroll
        for (int k2 = 0; k2 < 4; ++k2) {
            // convert this k-pair's 4 rows once; reused across 4 trajectories
            const h16x2 p0 = bch2(cw[k2].x);
            const h16x2 p1 = bch2(cw[k2].y);
            const h16x2 p2 = bch2(cw[k2].z);
            const h16x2 p3 = bch2(cw[k2].w);
            const float w0e = (float)p0.x, w0o = (float)p0.y;
            const float w1e = (float)p1.x, w1o = (float)p1.y;
            const float w2e = (float)p2.x, w2o = (float)p2.y;
            const float w3e = (float)p3.x, w3o = (float)p3.y;
            #pragma unroll
            for (int t4 = 0; t4 < TRAJ; ++t4) {
                const float2 h = *(const float2*)(h2s + t4 * 128 + kc * 8 + 2 * k2);
                f32x4 a = acc[t4];
                a.x = fmaf(h.x, w0e, a.x); a.x = fmaf(h.y, w0o, a.x);
                a.y = fmaf(h.x, w1e, a.y); a.y = fmaf(h.y, w1o, a.y);
                a.z = fmaf(h.x, w2e, a.z); a.z = fmaf(h.y, w2o, a.z);
                a.w = fmaf(h.x, w3e, a.w); a.w = fmaf(h.y, w3o, a.w);
                acc[t4] = a;
            }
        }
    }

    // einsum over d: n = 4*tid+j => h = tid>>3, d = 4*(tid&7)+j.
    const int dbase = 4 * (tid & 7);
    float part[TRAJ];
    #pragma unroll
    for (int t4 = 0; t4 < TRAJ; ++t4) {
        const float4 dx = *(const float4*)(dXs + t4 * 32 + dbase);
        part[t4] = (acc[t4].x + fb3r.x) * dx.x + (acc[t4].y + fb3r.y) * dx.y +
                   (acc[t4].z + fb3r.z) * dx.z + (acc[t4].w + fb3r.w) * dx.w;
    }
    #pragma unroll
    for (int m = 1; m < 8; m <<= 1) {
        #pragma unroll
        for (int t4 = 0; t4 < TRAJ; ++t4) part[t4] += __shfl_xor(part[t4], m, 64);
    }
    if ((tid & 7) == 0) {
        const int h = tid >> 3;
        #pragma unroll
        for (int t4 = 0; t4 < TRAJ; ++t4) kout[t4 * 64 + h] = part[t4];
    }
    __syncthreads();
}

__global__ __launch_bounds__(NT, 1)
void cde_kernel(const float* __restrict__ ts,
                const float* __restrict__ coef_d, const float* __restrict__ coef_c,
                const float* __restrict__ coef_b, const float* __restrict__ coef_a,
                const float* __restrict__ iW1, const float* __restrict__ ib1,
                const float* __restrict__ iW2, const float* __restrict__ ib2,
                const float* __restrict__ iW3, const float* __restrict__ ib3,
                const float* __restrict__ fW1, const float* __restrict__ fb1,
                const float* __restrict__ fW2, const float* __restrict__ fb2,
                const float* __restrict__ fb3,
                const float* __restrict__ dW1, const float* __restrict__ db1,
                const float* __restrict__ dW2, const float* __restrict__ db2,
                const float* __restrict__ dW3, const float* __restrict__ db3,
                const uint4* __restrict__ fW3P,
                float* __restrict__ outp)
{
    // weight region is a union across phases: init (112KB) / main (96KB) / decoder (104KB)
    __shared__ float wreg[28672];
    __shared__ float h1s[TRAJ * 128], h2s[TRAJ * 128];
    __shared__ float ys[TRAJ * 64], ys2[TRAJ * 64], k1s[TRAJ * 64], k2s[TRAJ * 64];
    __shared__ float dXs[TRAJ * 32], a0s[TRAJ * 32];
    __shared__ float fb1s[128], fb2s[128];

    const int tid = threadIdx.x;
    const int bbase = blockIdx.x * TRAJ;

    const float ts0 = ts[0];
    const float dt = (ts[Lk - 1] - ts0) / (float)NSTEPS;
    const float4 fb3r = *((const float4*)fb3 + tid);         // n = 4*tid .. 4*tid+3

    // ---- initial condition: y0 = sp(MLP_i(coef_a[:,0,:])) ----
    if (tid < TRAJ * 32) {
        const int t = tid >> 5, d = tid & 31;
        a0s[t * 32 + d] = coef_a[((size_t)(bbase + t) * 199) * 32 + d];
    }
    stage_T<128, 32>(iW1, wreg);                       // iT1 [32][128]
    stage_T<128, 128>(iW2, wreg + 32 * 128);           // iT2 [128][128]
    stage_T<64, 128>(iW3, wreg + 32 * 128 + 128 * 128);// iT3 [128][64]
    if (tid < 128) { fb1s[tid] = fb1[tid]; fb2s[tid] = fb2[tid]; }
    __syncthreads();
    mlp_layer<32, 128, 1>(wreg, ib1, a0s, 32, h1s, 128);
    __syncthreads();
    mlp_layer<128, 128, 1>(wreg + 32 * 128, ib2, h1s, 128, h2s, 128);
    __syncthreads();
    mlp_layer<128, 64, 1>(wreg + 32 * 128 + 128 * 128, ib3, h2s, 128, ys, 64);
    __syncthreads();

    // ---- stage vector-field small weights (resident for all 200 evals) ----
    stage_T<128, 64>(fW1, wreg);                       // wT1 [64][128]
    stage_T<128, 128>(fW2, wreg + 64 * 128);           // wT2 [128][128]
    __syncthreads();

    // ---- Heun over 100 fixed steps ----
    for (int step = 0; step < NSTEPS; ++step) {
        const float t1 = ts0 + (float)step * dt;
        evalvf(t1, ys, k1s, wreg, wreg + 64 * 128, fb1s, fb2s, h1s, h2s, dXs,
               ts, coef_b, coef_c, coef_d, bbase, fW3P, fb3r);
        if (tid < TRAJ * 64) ys2[tid] = ys[tid] + dt * k1s[tid];
        __syncthreads();
        evalvf(t1 + dt, ys2, k2s, wreg, wreg + 64 * 128, fb1s, fb2s, h1s, h2s, dXs,
               ts, coef_b, coef_c, coef_d, bbase, fW3P, fb3r);
        if (tid < TRAJ * 64) ys[tid] += 0.5f * dt * (k1s[tid] + k2s[tid]);
        __syncthreads();
    }

    // ---- decoder: Linear->relu->Linear->relu->Linear ----
    stage_T<128, 64>(dW1, wreg);                          // dT1 [64][128]
    stage_T<128, 128>(dW2, wreg + 64 * 128);              // dT2 [128][128]
    stage_T<16, 128>(dW3, wreg + 64 * 128 + 128 * 128);   // dT3 [128][16]
    __syncthreads();
    mlp_layer<64, 128, 2>(wreg, db1, ys, 64, h1s, 128);
    __syncthreads();
    mlp_layer<128, 128, 2>(wreg + 64 * 128, db2, h1s, 128, h2s, 128);
    __syncthreads();
    mlp_layer<128, 16, 0>(wreg + 64 * 128 + 128 * 128, db3, h2s, 128,
                          outp + (size_t)bbase * 16, 16);
}

extern "C" void kernel_launch(void* const* d_in, const int* in_sizes, int n_in,
                              void* d_out, int out_size, void* d_ws, size_t ws_size,
                              hipStream_t stream) {
    (void)in_sizes; (void)n_in; (void)out_size; (void)ws_size;
    const float* ts     = (const float*)d_in[0];
    const float* coef_d = (const float*)d_in[1];
    const float* coef_c = (const float*)d_in[2];
    const float* coef_b = (const float*)d_in[3];
    const float* coef_a = (const float*)d_in[4];
    const float* iW1 = (const float*)d_in[5];  const float* ib1 = (const float*)d_in[6];
    const float* iW2 = (const float*)d_in[7];  const float* ib2 = (const float*)d_in[8];
    const float* iW3 = (const float*)d_in[9];  const float* ib3 = (const float*)d_in[10];
    const float* fW1 = (const float*)d_in[11]; const float* fb1 = (const float*)d_in[12];
    const float* fW2 = (const float*)d_in[13]; const float* fb2 = (const float*)d_in[14];
    const float* fW3 = (const float*)d_in[15]; const float* fb3 = (const float*)d_in[16];
    const float* dW1 = (const float*)d_in[17]; const float* db1 = (const float*)d_in[18];
    const float* dW2 = (const float*)d_in[19]; const float* db2 = (const float*)d_in[20];
    const float* dW3 = (const float*)d_in[21]; const float* db3 = (const float*)d_in[22];

    unsigned int* fW3P = (unsigned int*)d_ws;   // 512 KB: packed fp16 fW3

    fw3_pack<<<512, 256, 0, stream>>>(fW3, fW3P);
    cde_kernel<<<256, NT, 0, stream>>>(ts, coef_d, coef_c, coef_b, coef_a,
                                       iW1, ib1, iW2, ib2, iW3, ib3,
                                       fW1, fb1, fW2, fb2, fb3,
                                       dW1, db1, dW2, db2, dW3, db3,
                                       (const uint4*)fW3P, (float*)d_out);
}